// Round 1
// baseline (94.003 us; speedup 1.0000x reference)
//
#include <hip/hip_runtime.h>

#define N_GENES 768
#define H 128
#define TILE 48      // 48x48 pair tile per block -> 16x16 = 256 blocks exactly
#define LDP 132      // f32 LDS row stride: +4 keeps 16B alignment, breaks bank aliasing
#define LDPH 136     // f16 LDS row stride in halves: 272B rows, 16B-aligned, bank shift 4

typedef float    f2 __attribute__((ext_vector_type(2)));
typedef _Float16 h2 __attribute__((ext_vector_type(2)));
typedef _Float16 h8 __attribute__((ext_vector_type(8)));

// ---------------------------------------------------------------------------
// Kernel A: per-gene projections, f64 accumulate (bit-identical math to the
// verified version). Additionally block 0 emits the u/v weight-difference
// vectors so grn_main can fetch them through the scalar cache instead of LDS.
//   AiB[i][m] = sum_k X[i][k]*W1[m][k] + b1[m]
//   Bjp[i][m] = sum_k X[i][k]*W1[m][H+k]
//   Yh [i][m] = f16( sum_k X[i][k]*Wb[k][m] )   (phase-1 affinity operand)
//   Xh [i][m] = f16( X[i][m] )
//   W2u[m] = W2[0][m]-W2[2][m],  W2v[m] = W2[0][m]-W2[1][m]
// ---------------------------------------------------------------------------
__global__ __launch_bounds__(128) void grn_pre(
    const float* __restrict__ X, const float* __restrict__ W1,
    const float* __restrict__ b1, const float* __restrict__ Wb,
    const float* __restrict__ W2,
    float* __restrict__ AiB, float* __restrict__ Bjp,
    _Float16* __restrict__ Yh, _Float16* __restrict__ Xh,
    float* __restrict__ W2u, float* __restrict__ W2v)
{
    const int m  = threadIdx.x;       // 0..127
    const int g0 = blockIdx.x * 3;    // first gene row of this block (256 blocks)

    if (blockIdx.x == 0) {            // tiny one-off: u/v weight diffs
        W2u[m] = W2[m] - W2[2 * H + m];
        W2v[m] = W2[m] - W2[H + m];
    }

    __shared__ float Xs[3][H];
    #pragma unroll
    for (int r = 0; r < 3; ++r) Xs[r][m] = X[(g0 + r) * H + m];
    __syncthreads();

    double aib[3] = {0, 0, 0}, bj[3] = {0, 0, 0}, y[3] = {0, 0, 0};
    const float4* W1a = (const float4*)(W1 + m * (2 * H));
    const float4* W1b = (const float4*)(W1 + m * (2 * H) + H);

    #pragma unroll 4
    for (int kq = 0; kq < H / 4; ++kq) {
        float4 wa = W1a[kq];
        float4 wb = W1b[kq];
        float wc[4];
        #pragma unroll
        for (int e = 0; e < 4; ++e) wc[e] = Wb[(kq * 4 + e) * H + m];  // coalesced across m
        const float* wae = &wa.x;
        const float* wbe = &wb.x;
        #pragma unroll
        for (int r = 0; r < 3; ++r) {
            float4 xr = *(const float4*)&Xs[r][kq * 4];
            const float* xe = &xr.x;
            #pragma unroll
            for (int e = 0; e < 4; ++e) {
                aib[r] += (double)xe[e] * (double)wae[e];
                bj[r]  += (double)xe[e] * (double)wbe[e];
                y[r]   += (double)xe[e] * (double)wc[e];
            }
        }
    }

    const double b1m = (double)b1[m];
    #pragma unroll
    for (int r = 0; r < 3; ++r) {
        AiB[(g0 + r) * H + m] = (float)(aib[r] + b1m);
        Bjp[(g0 + r) * H + m] = (float)bj[r];
        Yh [(g0 + r) * H + m] = (_Float16)(float)y[r];
        Xh [(g0 + r) * H + m] = (_Float16)Xs[r][m];
    }
}

__device__ __forceinline__ h2 hpair(h8 v, int p) { h2 r; r.x = v[2*p]; r.y = v[2*p+1]; return r; }

// ---------------------------------------------------------------------------
// Kernel B: fused main. 256 blocks (one/CU), 256 threads, 3x3 pairs/thread.
// Phase 1: affinity via f16 v_dot2 (separate f16 LDS buffers).
// Phase 2: u=l0-l2, v=l0-l1 with h=relu(a+b) packed, u/v FMA chains now
//          v_pk_fma_f32 {u,v} pairs — per-accumulator order identical to the
//          verified scalar chains (argmax-tie safe). Weights come from the
//          scalar cache (wave-uniform global loads), not LDS.
// T14: f32 tiles are issued to registers BEFORE phase 1 and written to LDS
//      after it, hiding the global-load latency under the dot2 loop.
// ---------------------------------------------------------------------------
__global__ __launch_bounds__(256) void grn_main(
    const float* __restrict__ AiB, const float* __restrict__ Bjp,
    const _Float16* __restrict__ Yh, const _Float16* __restrict__ Xh,
    const float* __restrict__ W2u, const float* __restrict__ W2v,
    const float* __restrict__ b2,  const float* __restrict__ bb,
    float* __restrict__ out)
{
    const int gj = blockIdx.x & 15;
    const int gi = blockIdx.x >> 4;
    const int tx = threadIdx.x;
    const int it = tx >> 4;   // 0..15 -> i rows it+{0,16,32}
    const int jt = tx & 15;   // 0..15 -> j cols jt+{0,16,32}

    __shared__ _Float16 sYh[TILE * LDPH];   // phase-1 left  (f16)
    __shared__ _Float16 sXh[TILE * LDPH];   // phase-1 right (f16)
    __shared__ float    sA [TILE * LDP];    // phase-2 AiB tile
    __shared__ float    sB [TILE * LDP];    // phase-2 Bjp tile

    // ---- stage f16 tiles into LDS ----
    {
        const _Float16* srcY = Yh + gi * TILE * H;
        const _Float16* srcX = Xh + gj * TILE * H;
        #pragma unroll
        for (int t = 0; t < 3; ++t) {
            int idx = tx + t * 256;       // 0..767
            int row = idx >> 4;           // 16 h8 per row
            int c8  = idx & 15;
            *(h8*)&sYh[row * LDPH + c8 * 8] = *(const h8*)&srcY[row * H + c8 * 8];
            *(h8*)&sXh[row * LDPH + c8 * 8] = *(const h8*)&srcX[row * H + c8 * 8];
        }
    }

    // ---- issue f32 tile loads now; latency hides under phase-1 compute ----
    float4 aReg[6], bReg[6];
    {
        const float* srcA = AiB + gi * TILE * H;
        const float* srcB = Bjp + gj * TILE * H;
        #pragma unroll
        for (int t = 0; t < 6; ++t) {
            int idx = tx + t * 256;       // 0..1535
            int row = idx >> 5;           // 32 float4 per row
            int c4  = idx & 31;
            aReg[t] = *(const float4*)&srcA[row * H + c4 * 4];
            bReg[t] = *(const float4*)&srcB[row * H + c4 * 4];
        }
    }

    __syncthreads();   // f16 tiles visible

    // ---- phase 1: affinity (f16 storage, f32 accumulate via v_dot2) ----
    float aff[3][3] = {};
    #pragma unroll 2
    for (int q = 0; q < H / 8; ++q) {
        h8 yv[3], xv[3];
        #pragma unroll
        for (int r = 0; r < 3; ++r) yv[r] = *(const h8*)&sYh[(it + 16 * r) * LDPH + q * 8];
        #pragma unroll
        for (int c = 0; c < 3; ++c) xv[c] = *(const h8*)&sXh[(jt + 16 * c) * LDPH + q * 8];
        #pragma unroll
        for (int r = 0; r < 3; ++r)
            #pragma unroll
            for (int c = 0; c < 3; ++c)
                #pragma unroll
                for (int p = 0; p < 4; ++p) {
#if __has_builtin(__builtin_amdgcn_fdot2)
                    aff[r][c] = __builtin_amdgcn_fdot2(hpair(yv[r], p), hpair(xv[c], p),
                                                       aff[r][c], false);
#else
                    h2 a = hpair(yv[r], p), b = hpair(xv[c], p);
                    aff[r][c] = fmaf((float)a.x, (float)b.x, aff[r][c]);
                    aff[r][c] = fmaf((float)a.y, (float)b.y, aff[r][c]);
#endif
                }
    }

    // ---- write f32 tiles to LDS (vmcnt waits land here, after phase 1) ----
    #pragma unroll
    for (int t = 0; t < 6; ++t) {
        int idx = tx + t * 256;
        int row = idx >> 5;
        int c4  = idx & 31;
        *(float4*)&sA[row * LDP + c4 * 4] = aReg[t];
        *(float4*)&sB[row * LDP + c4 * 4] = bReg[t];
    }
    __syncthreads();

    // ---- phase 2: logit differences, packed {u,v} accumulators ----
    const float u0 = b2[0] - b2[2];
    const float v0 = b2[0] - b2[1];
    f2 uv[3][3];
    #pragma unroll
    for (int r = 0; r < 3; ++r)
        #pragma unroll
        for (int c = 0; c < 3; ++c) { uv[r][c].x = u0; uv[r][c].y = v0; }

    const float4* w0p = (const float4*)W2u;   // wave-uniform -> scalar cache
    const float4* w1p = (const float4*)W2v;
    const f2 zero2 = {0.0f, 0.0f};
    #pragma unroll 4
    for (int mq = 0; mq < H / 4; ++mq) {
        float4 w0 = w0p[mq];
        float4 w1 = w1p[mq];
        float4 av[3], bv[3];
        #pragma unroll
        for (int r = 0; r < 3; ++r) av[r] = *(const float4*)&sA[(it + 16 * r) * LDP + mq * 4];
        #pragma unroll
        for (int c = 0; c < 3; ++c) bv[c] = *(const float4*)&sB[(jt + 16 * c) * LDP + mq * 4];
        #pragma unroll
        for (int r = 0; r < 3; ++r) {
            f2 a01 = {av[r].x, av[r].y};
            f2 a23 = {av[r].z, av[r].w};
            #pragma unroll
            for (int c = 0; c < 3; ++c) {
                f2 b01 = {bv[c].x, bv[c].y};
                f2 b23 = {bv[c].z, bv[c].w};
                // packed relu(a+b): elementwise -> bit-identical to scalar
                f2 h01 = __builtin_elementwise_max(a01 + b01, zero2);
                f2 h23 = __builtin_elementwise_max(a23 + b23, zero2);
                // v_pk_fma_f32 {u,v}: each accumulator's chain keeps the
                // exact e=0..3 order of the verified scalar version
                f2 acc = uv[r][c];
                acc = __builtin_elementwise_fma((f2){h01.x, h01.x}, (f2){w0.x, w1.x}, acc);
                acc = __builtin_elementwise_fma((f2){h01.y, h01.y}, (f2){w0.y, w1.y}, acc);
                acc = __builtin_elementwise_fma((f2){h23.x, h23.x}, (f2){w0.z, w1.z}, acc);
                acc = __builtin_elementwise_fma((f2){h23.y, h23.y}, (f2){w0.w, w1.w}, acc);
                uv[r][c] = acc;
            }
        }
    }

    // ---- epilogue: sign select, bilinear bias, zero diagonal ----
    const float bbv = bb[0];
    #pragma unroll
    for (int r = 0; r < 3; ++r) {
        const int i = gi * TILE + it + 16 * r;
        #pragma unroll
        for (int c = 0; c < 3; ++c) {
            const int j = gj * TILE + jt + 16 * c;
            float A = aff[r][c] + bbv;
            float uu = uv[r][c].x, vv = uv[r][c].y;
            // cls0: vv>=0 && uu>=0 -> +A ; cls2: uu<0 && uu<vv -> -A ; else 0
            float s = (uu >= 0.0f && vv >= 0.0f) ? A
                    : ((uu < 0.0f && uu < vv) ? -A : 0.0f);
            if (i == j) s = 0.0f;
            out[i * N_GENES + j] = s;
        }
    }
}

extern "C" void kernel_launch(void* const* d_in, const int* in_sizes, int n_in,
                              void* d_out, int out_size, void* d_ws, size_t ws_size,
                              hipStream_t stream)
{
    const float* X  = (const float*)d_in[0];  // [768,128]
    const float* W1 = (const float*)d_in[1];  // [128,256]
    const float* b1 = (const float*)d_in[2];  // [128]
    const float* W2 = (const float*)d_in[3];  // [3,128]
    const float* b2 = (const float*)d_in[4];  // [3]
    const float* Wb = (const float*)d_in[5];  // [1,128,128]
    const float* bb = (const float*)d_in[6];  // [1]
    float* out = (float*)d_out;

    float* ws  = (float*)d_ws;
    float*     AiB = ws;                                   // 768*128 f32
    float*     Bjp = ws + N_GENES * H;                     // 768*128 f32
    _Float16*  Yh  = (_Float16*)(ws + 2 * N_GENES * H);    // 768*128 f16
    _Float16*  Xh  = Yh + N_GENES * H;                     // 768*128 f16
    float*     W2u = ws + 3 * N_GENES * H;                 // 128 f32
    float*     W2v = W2u + H;                              // 128 f32

    grn_pre <<<N_GENES / 3, 128, 0, stream>>>(X, W1, b1, Wb, W2, AiB, Bjp, Yh, Xh, W2u, W2v);
    grn_main<<<256,         256, 0, stream>>>(AiB, Bjp, Yh, Xh, W2u, W2v, b2, bb, out);
}

// Round 2
// 88.965 us; speedup vs baseline: 1.0566x; 1.0566x over previous
//
#include <hip/hip_runtime.h>

#define N_GENES 768
#define H 128
#define TILE 48      // 48x48 pair tile per block -> 16x16 = 256 blocks exactly
#define LDP 132      // f32 LDS row stride: +4 keeps 16B alignment, breaks bank aliasing
#define LDSA 50      // aff LDS row stride: 48+2 -> writes/reads <=2-way banks (free)

typedef float f32x4 __attribute__((ext_vector_type(4)));
typedef _Float16 h8 __attribute__((ext_vector_type(8)));

// ---------------------------------------------------------------------------
// Kernel A: per-gene projections, f64 accumulate. Round-0 math, but 256
// threads/block with split-K (two 64-long f64 chains combined in f64 via LDS)
// -> 4 waves/CU instead of 2, ~2x VALU throughput. (lo+hi)+b1 differs from
// the sequential chain by O(2^-52) relative - f32 cast unchanged.
//   AiB[i][m] = sum_k X[i][k]*W1[m][k] + b1[m]
//   Bjp[i][m] = sum_k X[i][k]*W1[m][H+k]
//   Yh [i][m] = f16( sum_k X[i][k]*Wb[k][m] )   (phase-1 affinity operand)
//   Xh [i][m] = f16( X[i][m] )
// ---------------------------------------------------------------------------
__global__ __launch_bounds__(256) void grn_pre(
    const float* __restrict__ X, const float* __restrict__ W1,
    const float* __restrict__ b1, const float* __restrict__ Wb,
    float* __restrict__ AiB, float* __restrict__ Bjp,
    _Float16* __restrict__ Yh, _Float16* __restrict__ Xh)
{
    const int tx = threadIdx.x;
    const int m  = tx & 127;          // output column
    const int h  = tx >> 7;           // K-half: waves 0,1 -> k 0..63; waves 2,3 -> k 64..127
    const int g0 = blockIdx.x * 3;    // first gene row of this block (256 blocks)

    __shared__ float  Xs[3 * H];
    __shared__ double parts[3][3][H]; // [quantity][row][m], written by h==1

    for (int idx = tx; idx < 3 * H; idx += 256) Xs[idx] = X[g0 * H + idx];
    __syncthreads();

    double aib[3] = {0, 0, 0}, bj[3] = {0, 0, 0}, y[3] = {0, 0, 0};
    const int kb = h * 64;
    const float4* W1a = (const float4*)(W1 + m * (2 * H) + kb);
    const float4* W1b = (const float4*)(W1 + m * (2 * H) + H + kb);

    #pragma unroll 4
    for (int kq = 0; kq < 16; ++kq) {
        float4 wa = W1a[kq];
        float4 wb = W1b[kq];
        float wc[4];
        #pragma unroll
        for (int e = 0; e < 4; ++e) wc[e] = Wb[(kb + kq * 4 + e) * H + m];  // coalesced across m
        const float* wae = &wa.x;
        const float* wbe = &wb.x;
        #pragma unroll
        for (int r = 0; r < 3; ++r) {
            float4 xr = *(const float4*)&Xs[r * H + kb + kq * 4];
            const float* xe = &xr.x;
            #pragma unroll
            for (int e = 0; e < 4; ++e) {
                aib[r] += (double)xe[e] * (double)wae[e];
                bj[r]  += (double)xe[e] * (double)wbe[e];
                y[r]   += (double)xe[e] * (double)wc[e];
            }
        }
    }

    if (h == 1) {
        #pragma unroll
        for (int r = 0; r < 3; ++r) {
            parts[0][r][m] = aib[r];
            parts[1][r][m] = bj[r];
            parts[2][r][m] = y[r];
        }
    }
    __syncthreads();

    if (h == 0) {
        const double b1m = (double)b1[m];
        #pragma unroll
        for (int r = 0; r < 3; ++r) {
            double A = aib[r] + parts[0][r][m];
            double B = bj[r]  + parts[1][r][m];
            double Y = y[r]   + parts[2][r][m];
            AiB[(g0 + r) * H + m] = (float)(A + b1m);
            Bjp[(g0 + r) * H + m] = (float)B;
            Yh [(g0 + r) * H + m] = (_Float16)(float)Y;
            Xh [(g0 + r) * H + m] = (_Float16)Xs[r * H + m];
        }
    }
}

// ---------------------------------------------------------------------------
// Kernel B: fused main. 256 blocks (one/CU), 256 threads, 3x3 pairs/thread.
// Phase 1: affinity = Y.X^T via v_mfma_f32_16x16x32_f16 - 9 16x16 tiles over
//          4 waves, fragments read DIRECTLY from global (L2-hot), result
//          routed to phase-2 thread mapping through sAff in LDS.
// Phase 2: u=l0-l2, v=l0-l1 with h=relu(a+b); identical scalar FMA chains to
//          the verified round-0 kernel (argmax-tie safety). sW stays in LDS.
// f32 tiles are issued to registers before the MFMA phase and ds-written
// after it (short register lifetime, latency hidden under MFMA issue).
// Single __syncthreads() in the whole kernel.
// ---------------------------------------------------------------------------
__global__ __launch_bounds__(256) void grn_main(
    const float* __restrict__ AiB, const float* __restrict__ Bjp,
    const _Float16* __restrict__ Yh, const _Float16* __restrict__ Xh,
    const float* __restrict__ W2,  const float* __restrict__ b2,
    const float* __restrict__ bb,  float* __restrict__ out)
{
    const int gj = blockIdx.x & 15;
    const int gi = blockIdx.x >> 4;
    const int tx = threadIdx.x;
    const int it = tx >> 4;   // 0..15 -> i rows it+{0,16,32}
    const int jt = tx & 15;   // 0..15 -> j cols jt+{0,16,32}
    const int wid = tx >> 6;  // wave id 0..3
    const int l   = tx & 63;  // lane

    __shared__ float sA [TILE * LDP];    // phase-2 AiB tile
    __shared__ float sB [TILE * LDP];    // phase-2 Bjp tile
    __shared__ float sW [2 * H];         // [0..127]=W2[0]-W2[2] (u), [128..255]=W2[0]-W2[1] (v)
    __shared__ float sAff[TILE * LDSA];  // affinity, MFMA layout -> thread layout

    if (tx < H) {
        sW[tx]     = W2[tx] - W2[2 * H + tx];
        sW[H + tx] = W2[tx] - W2[H + tx];
    }

    // ---- issue f32 tile loads now; latency hides under the MFMA phase ----
    float4 aReg[6], bReg[6];
    {
        const float* srcA = AiB + gi * TILE * H;
        const float* srcB = Bjp + gj * TILE * H;
        #pragma unroll
        for (int t = 0; t < 6; ++t) {
            int idx = tx + t * 256;       // 0..1535
            int row = idx >> 5;           // 32 float4 per row
            int c4  = idx & 31;
            aReg[t] = *(const float4*)&srcA[row * H + c4 * 4];
            bReg[t] = *(const float4*)&srcB[row * H + c4 * 4];
        }
    }

    // ---- phase 1: affinity via MFMA, fragments straight from global ----
    {
        const _Float16* Ybase = Yh + (gi * TILE) * H;
        const _Float16* Xbase = Xh + (gj * TILE) * H;
        const int ro = l & 15;            // fragment row within 16
        const int ko = (l >> 4) * 8;      // fragment k-offset
        for (int t = wid; t < 9; t += 4) {
            const int ti = t / 3, tj = t - ti * 3;
            f32x4 acc = {0.f, 0.f, 0.f, 0.f};
            #pragma unroll
            for (int kk = 0; kk < 4; ++kk) {
                h8 a = *(const h8*)&Ybase[(ti * 16 + ro) * H + kk * 32 + ko];
                h8 b = *(const h8*)&Xbase[(tj * 16 + ro) * H + kk * 32 + ko];
                acc = __builtin_amdgcn_mfma_f32_16x16x32_f16(a, b, acc, 0, 0, 0);
            }
            // C/D layout: col = lane&15, row = (lane>>4)*4 + reg
            const int r0 = ti * 16 + ((l >> 4) << 2);
            const int c0 = tj * 16 + ro;
            #pragma unroll
            for (int v = 0; v < 4; ++v) sAff[(r0 + v) * LDSA + c0] = acc[v];
        }
    }

    // ---- write staged f32 tiles to LDS ----
    #pragma unroll
    for (int t = 0; t < 6; ++t) {
        int idx = tx + t * 256;
        int row = idx >> 5;
        int c4  = idx & 31;
        *(float4*)&sA[row * LDP + c4 * 4] = aReg[t];
        *(float4*)&sB[row * LDP + c4 * 4] = bReg[t];
    }
    __syncthreads();

    // ---- phase 2: logit differences (verified round-0 form) ----
    const float u0 = b2[0] - b2[2];
    const float v0 = b2[0] - b2[1];
    float u[3][3], v[3][3];
    #pragma unroll
    for (int r = 0; r < 3; ++r)
        #pragma unroll
        for (int c = 0; c < 3; ++c) { u[r][c] = u0; v[r][c] = v0; }

    typedef float f2 __attribute__((ext_vector_type(2)));
    const f2 zero2 = {0.0f, 0.0f};
    #pragma unroll 4
    for (int mq = 0; mq < H / 4; ++mq) {
        float4 w0 = *(const float4*)&sW[mq * 4];
        float4 w1 = *(const float4*)&sW[H + mq * 4];
        float4 av[3], bv[3];
        #pragma unroll
        for (int r = 0; r < 3; ++r) av[r] = *(const float4*)&sA[(it + 16 * r) * LDP + mq * 4];
        #pragma unroll
        for (int c = 0; c < 3; ++c) bv[c] = *(const float4*)&sB[(jt + 16 * c) * LDP + mq * 4];
        #pragma unroll
        for (int r = 0; r < 3; ++r) {
            f2 a01 = {av[r].x, av[r].y};
            f2 a23 = {av[r].z, av[r].w};
            #pragma unroll
            for (int c = 0; c < 3; ++c) {
                f2 b01 = {bv[c].x, bv[c].y};
                f2 b23 = {bv[c].z, bv[c].w};
                // packed relu(a+b): elementwise -> bit-identical to scalar
                f2 h01 = __builtin_elementwise_max(a01 + b01, zero2);
                f2 h23 = __builtin_elementwise_max(a23 + b23, zero2);
                // scalar FMA chains in the verified e=0..3 order (tie safety)
                float uu = u[r][c], vv = v[r][c];
                uu = fmaf(h01.x, w0.x, uu); vv = fmaf(h01.x, w1.x, vv);
                uu = fmaf(h01.y, w0.y, uu); vv = fmaf(h01.y, w1.y, vv);
                uu = fmaf(h23.x, w0.z, uu); vv = fmaf(h23.x, w1.z, vv);
                uu = fmaf(h23.y, w0.w, uu); vv = fmaf(h23.y, w1.w, vv);
                u[r][c] = uu; v[r][c] = vv;
            }
        }
    }

    // ---- epilogue: sign select, bilinear bias, zero diagonal ----
    const float bbv = bb[0];
    #pragma unroll
    for (int r = 0; r < 3; ++r) {
        const int i = gi * TILE + it + 16 * r;
        #pragma unroll
        for (int c = 0; c < 3; ++c) {
            const int j = gj * TILE + jt + 16 * c;
            float A = sAff[(it + 16 * r) * LDSA + (jt + 16 * c)] + bbv;
            float uu = u[r][c], vv = v[r][c];
            // cls0: vv>=0 && uu>=0 -> +A ; cls2: uu<0 && uu<vv -> -A ; else 0
            float s = (uu >= 0.0f && vv >= 0.0f) ? A
                    : ((uu < 0.0f && uu < vv) ? -A : 0.0f);
            if (i == j) s = 0.0f;
            out[i * N_GENES + j] = s;
        }
    }
}

extern "C" void kernel_launch(void* const* d_in, const int* in_sizes, int n_in,
                              void* d_out, int out_size, void* d_ws, size_t ws_size,
                              hipStream_t stream)
{
    const float* X  = (const float*)d_in[0];  // [768,128]
    const float* W1 = (const float*)d_in[1];  // [128,256]
    const float* b1 = (const float*)d_in[2];  // [128]
    const float* W2 = (const float*)d_in[3];  // [3,128]
    const float* b2 = (const float*)d_in[4];  // [3]
    const float* Wb = (const float*)d_in[5];  // [1,128,128]
    const float* bb = (const float*)d_in[6];  // [1]
    float* out = (float*)d_out;

    float* ws  = (float*)d_ws;
    float*     AiB = ws;                                   // 768*128 f32
    float*     Bjp = ws + N_GENES * H;                     // 768*128 f32
    _Float16*  Yh  = (_Float16*)(ws + 2 * N_GENES * H);    // 768*128 f16
    _Float16*  Xh  = Yh + N_GENES * H;                     // 768*128 f16

    grn_pre <<<N_GENES / 3, 256, 0, stream>>>(X, W1, b1, Wb, AiB, Bjp, Yh, Xh);
    grn_main<<<256,         256, 0, stream>>>(AiB, Bjp, Yh, Xh, W2, b2, bb, out);
}